// Round 14
// baseline (194.640 us; speedup 1.0000x reference)
//
#include <hip/hip_runtime.h>

#define FEAT 2048
#define HWD 14
#define NPIX 196          // 14*14
#define C_CLS 20
#define M_DIM 64
#define U_DIM 128
#define B_SZ 4
#define K_REL 19          // C-1
#define NPOOL 49          // 7*7

typedef __attribute__((ext_vector_type(8))) short bf16x8s;
typedef __attribute__((ext_vector_type(8))) unsigned short ushort8v;
typedef __attribute__((ext_vector_type(4))) float f32x4;
typedef __attribute__((ext_vector_type(4))) unsigned int uint4v;

__device__ inline unsigned short f2bf(float f) {
    unsigned u = __builtin_bit_cast(unsigned, f);
    unsigned r = (u + 0x7FFF + ((u >> 16) & 1)) >> 16;   // RNE
    return (unsigned short)r;
}

// ---------------------------------------------------------------------------
// Kernel 1: prep (R10-verified) + zeroing the 80 last-arrival counters.
// ---------------------------------------------------------------------------
__global__ __launch_bounds__(256) void prep_kernel(
        const float* __restrict__ x, const float* __restrict__ Wp,
        const float* __restrict__ Wg,
        unsigned short* __restrict__ xts, unsigned short* __restrict__ Awp,
        unsigned short* __restrict__ Awg, int* __restrict__ cnt) {
    __shared__ unsigned short SM[128 * 136];   // 34,816 B (aliased per branch)
    const int blk = blockIdx.x;
    const int tid = threadIdx.x;
    const int lane = tid & 63, wv = tid >> 6;
    const int l15 = lane & 15, lq = lane >> 4;

    if (blk == 0 && tid < 80) cnt[tid] = 0;    // last-arrival counters

    if (blk < 128) {
        unsigned short (*T)[210] = (unsigned short (*)[210])SM;
        const int b = blk >> 5;
        const int s = blk & 31;
        const float* xb = x + ((size_t)b * FEAT + s * 64) * NPIX;
        for (int i = tid; i < 64 * NPIX; i += 256) {
            int kk = i / NPIX, hw = i - kk * NPIX;
            T[kk][hw] = f2bf(xb[(size_t)kk * NPIX + hw]);
        }
        __syncthreads();
        unsigned short* ob = xts + ((size_t)(b * 32 + s)) * 1664 * 8;
        for (int i = tid; i < 1664; i += 256) {
            int ch = i / 208, row = i - ch * 208;
            ushort8v o;
#pragma unroll
            for (int j = 0; j < 8; j++)
                o[j] = (row < NPIX) ? T[ch * 8 + j][row] : (unsigned short)0;
            *(ushort8v*)(ob + (size_t)i * 8) = o;
        }
    } else if (blk < 288) {
        unsigned short (*TP)[264] = (unsigned short (*)[264])SM;
        const int p = blk - 128;
        const int c = p >> 3, kc = p & 7;
        const float* wsrc = Wp + ((size_t)c * M_DIM) * FEAT + kc * 256;
#pragma unroll
        for (int it = 0; it < 16; it++) {
            int i4 = tid + it * 256;           // 0..4095
            int m = i4 >> 6, c4 = i4 & 63;
            float4 v = *(const float4*)(wsrc + (size_t)m * FEAT + c4 * 4);
            TP[m][c4 * 4 + 0] = f2bf(v.x);
            TP[m][c4 * 4 + 1] = f2bf(v.y);
            TP[m][c4 * 4 + 2] = f2bf(v.z);
            TP[m][c4 * 4 + 3] = f2bf(v.w);
        }
        __syncthreads();
#pragma unroll
        for (int fr = 0; fr < 8; fr++) {
            int ss = wv;
            int fi = fr;
            int rt = fi >> 1, f = fi & 1;
            int m = rt * 16 + l15;
            int kl = ss * 64 + f * 32 + lq * 8;
            bf16x8s vfrag = *(const bf16x8s*)(&TP[m][kl]);
            int s = kc * 4 + ss;
            *(bf16x8s*)(Awp + (((size_t)(c * 32 + s) * 8 + fi) * 64 + lane) * 8) = vfrag;
        }
    } else {
        unsigned short (*TG)[136] = (unsigned short (*)[136])SM;
        const int ck = blk - 288;              // 0..379
        const float* gsrc = Wg + (size_t)ck * U_DIM * 128;
#pragma unroll
        for (int it = 0; it < 16; it++) {
            int i4 = tid + it * 256;           // 0..4095
            int u = i4 >> 5, c4 = i4 & 31;
            float4 v = *(const float4*)(gsrc + (size_t)u * 128 + c4 * 4);
            TG[u][c4 * 4 + 0] = f2bf(v.x);
            TG[u][c4 * 4 + 1] = f2bf(v.y);
            TG[u][c4 * 4 + 2] = f2bf(v.z);
            TG[u][c4 * 4 + 3] = f2bf(v.w);
        }
        __syncthreads();
#pragma unroll
        for (int fr = 0; fr < 8; fr++) {
            int fi = fr;
            int ut = fi >> 2, ks = fi & 3;
            int u = wv * 32 + ut * 16 + l15;
            int mm = ks * 32 + lq * 8;
            bf16x8s vfrag = *(const bf16x8s*)(&TG[u][mm]);
            *(bf16x8s*)(Awg + (((size_t)(ck * 4 + wv) * 8 + fi) * 64 + lane) * 8) = vfrag;
        }
    }
}

// ---------------------------------------------------------------------------
// Kernel 2: MERGED gemm + phases (R13-verified), 1D grid of 80 with
// bijective XCD swizzle (80 = 8 x 10): each XCD gets 10 consecutive flats
// sharing the same b -> xts[b] stays in that XCD's L2.
// ---------------------------------------------------------------------------
__global__ __launch_bounds__(512) void gemmphase_kernel(
        const unsigned short* __restrict__ xts,
        const unsigned short* __restrict__ Awp,
        const float* __restrict__ Wstn,
        const float* __restrict__ bstn,
        unsigned short* __restrict__ x_objT) {
    __shared__ __align__(16) char smem[78336];
    float* xs     = (float*)smem;              // [64][209] = 53,504 B
    float* pooled = (float*)(smem + 53504);    // [3136]    = 12,544 B
    float* red    = (float*)(smem + 66048);    // [6][512]  = 12,288 B

    const int flat = (blockIdx.x & 7) * 10 + (blockIdx.x >> 3);   // bijective
    const int c = flat % C_CLS, b = flat / C_CLS;
    const int tid = threadIdx.x;
    const int lane = tid & 63, wv = tid >> 6;
    const int l15 = lane & 15, lq = lane >> 4;
    const int kh = wv >> 2;                         // K-half
    const int cg = wv & 3;                          // col group
    const int t0 = (cg == 0) ? 0 : (3 * cg + 1);    // {0,4,7,10}
    const int nt = (cg == 0) ? 4 : 3;

    const unsigned short* xsrc = xts + (size_t)b * 32 * 1664 * 8;
    const unsigned short* asrc = Awp + (size_t)c * 256 * 64 * 8;
    const int s0 = kh * 16;

    bf16x8s A0[8], A1[8], B0[8], B1[8];
    auto aload = [&](int s, bf16x8s (&A)[8]) {
#pragma unroll
        for (int fi = 0; fi < 8; fi++)
            A[fi] = *(const bf16x8s*)(asrc + (((size_t)s * 8 + fi) * 64 + lane) * 8);
    };
    auto bload = [&](int s, bf16x8s (&B)[8]) {
#pragma unroll
        for (int q = 0; q < 4; q++) {
            if (q < nt) {
#pragma unroll
                for (int f = 0; f < 2; f++)
                    B[q * 2 + f] = *(const bf16x8s*)(xsrc +
                        ((size_t)s * 1664 + (f * 4 + lq) * 208 + (t0 + q) * 16 + l15) * 8);
            }
        }
    };

    f32x4 acc[4][4];   // [col-tile q][row-frag rt]
#pragma unroll
    for (int q = 0; q < 4; q++)
#pragma unroll
        for (int rt = 0; rt < 4; rt++) acc[q][rt] = (f32x4){0.f, 0.f, 0.f, 0.f};

    auto compute = [&](bf16x8s (&A)[8], bf16x8s (&B)[8]) {
#pragma unroll
        for (int q = 0; q < 4; q++) {
            if (q < nt) {
#pragma unroll
                for (int rt = 0; rt < 4; rt++)
#pragma unroll
                    for (int f = 0; f < 2; f++)
                        acc[q][rt] = __builtin_amdgcn_mfma_f32_16x16x32_bf16(
                            A[rt * 2 + f], B[q * 2 + f], acc[q][rt], 0, 0, 0);
            }
        }
    };

    aload(s0, A0); bload(s0, B0);
#pragma unroll
    for (int sp = 0; sp < 8; sp++) {
        aload(s0 + 2 * sp + 1, A1); bload(s0 + 2 * sp + 1, B1);
        compute(A0, B0);
        if (sp < 7) { aload(s0 + 2 * sp + 2, A0); bload(s0 + 2 * sp + 2, B0); }
        compute(A1, B1);
    }

    // K-half reduce in LDS: kh0 writes, kh1 adds (disjoint per-thread addrs).
    if (kh == 0) {
#pragma unroll
        for (int q = 0; q < 4; q++) {
            if (q < nt) {
                int tt = t0 + q;
#pragma unroll
                for (int rt = 0; rt < 4; rt++)
#pragma unroll
                    for (int r = 0; r < 4; r++)
                        xs[(rt * 16 + lq * 4 + r) * 209 + tt * 16 + l15] = acc[q][rt][r];
            }
        }
    }
    __syncthreads();
    if (kh == 1) {
#pragma unroll
        for (int q = 0; q < 4; q++) {
            if (q < nt) {
                int tt = t0 + q;
#pragma unroll
                for (int rt = 0; rt < 4; rt++)
#pragma unroll
                    for (int r = 0; r < 4; r++)
                        xs[(rt * 16 + lq * 4 + r) * 209 + tt * 16 + l15] += acc[q][rt][r];
            }
        }
    }
    __syncthreads();

    // pool
    for (int i = tid; i < 3136; i += 512) {
        int m = i / NPOOL, p = i - m * NPOOL;
        int ph = p / 7, pw = p - ph * 7;
        const float* bp = &xs[m * 209 + ph * 2 * HWD + pw * 2];
        float v = fmaxf(fmaxf(bp[0], bp[1]), fmaxf(bp[HWD], bp[HWD + 1]));
        pooled[i] = fmaxf(v, 0.f);
    }
    __syncthreads();

    // theta
    float sj[6] = {0, 0, 0, 0, 0, 0};
#pragma unroll
    for (int it = 0; it < 7; it++) {
        int kk = tid + it * 512;
        if (kk < 3136) {
            float f = pooled[kk];
#pragma unroll
            for (int j = 0; j < 6; j++)
                sj[j] += f * Wstn[((size_t)c * 6 + j) * 3136 + kk];
        }
    }
#pragma unroll
    for (int j = 0; j < 6; j++) red[j * 512 + tid] = sj[j];
    __syncthreads();
    for (int off = 256; off > 0; off >>= 1) {
        if (tid < off) {
#pragma unroll
            for (int j = 0; j < 6; j++)
                red[j * 512 + tid] += red[j * 512 + tid + off];
        }
        __syncthreads();
    }
    float th[6];
#pragma unroll
    for (int j = 0; j < 6; j++) th[j] = red[j * 512] + bstn[c * 6 + j];

    // sample -> x_objT[b,c,hw(208),m]; zero-pad rows 196..207
    unsigned short* obase = x_objT + ((size_t)(b * C_CLS + c) * 208) * 64;
    for (int i = tid; i < 12 * 64; i += 512)
        obase[(size_t)(NPIX + i / 64) * 64 + (i & 63)] = 0;

    const int m = tid & 63;
    const int hwg = tid >> 6;                  // 0..7
    unsigned short* ob = obase + m;
    const float* xrow = &xs[m * 209];
    for (int it = 0; it < 25; it++) {
        int hw = hwg + it * 8;
        if (hw >= NPIX) break;                 // wave-uniform
        int h = hw / HWD, w = hw - h * HWD;
        float fx = -1.f + w * (2.f / 13.f);
        float fy = -1.f + h * (2.f / 13.f);
        float gxn = th[0] * fx + th[1] * fy + th[2];
        float gyn = th[3] * fx + th[4] * fy + th[5];
        float gx = (gxn + 1.f) * 0.5f * (HWD - 1);
        float gy = (gyn + 1.f) * 0.5f * (HWD - 1);
        float x0f = floorf(gx), y0f = floorf(gy);
        int x0 = (int)x0f, y0 = (int)y0f;
        int x1 = x0 + 1, y1 = y0 + 1;
        auto gat = [&](int yi, int xi) -> float {
            bool v = (yi >= 0) & (yi < HWD) & (xi >= 0) & (xi < HWD);
            int yc = min(max(yi, 0), HWD - 1);
            int xc = min(max(xi, 0), HWD - 1);
            return v ? xrow[yc * HWD + xc] : 0.f;
        };
        float xw1 = (float)x1 - gx, xw0 = gx - (float)x0;
        float yw1 = (float)y1 - gy, yw0 = gy - (float)y0;
        float val = gat(y0, x0) * xw1 * yw1 + gat(y0, x1) * xw0 * yw1 +
                    gat(y1, x0) * xw1 * yw0 + gat(y1, x1) * xw0 * yw0;
        ob[(size_t)hw * 64] = f2bf(val);
    }
}

// ---------------------------------------------------------------------------
// Kernel 3: relation (R10-verified core) + fused final via last-block-arrival.
// 1D grid 1520 = 8 x 190 bijective XCD swizzle: each XCD's 190 consecutive
// flats cover 10 (c,b) groups -> x_objT[b] L2-resident.
// After writing partial: threadfence + atomicAdd(cnt[bc]); the 19th arrival
// sums all k in fixed order (deterministic) and writes out[bc].
// ---------------------------------------------------------------------------
#define MP 136
__global__ __launch_bounds__(256) void relation_mfma_kernel(
        const unsigned short* __restrict__ x_objT,
        const unsigned short* __restrict__ Awg,
        float* __restrict__ partial,
        const float* __restrict__ wphi, const float* __restrict__ bphi,
        int* __restrict__ cnt, float* __restrict__ out) {
    __shared__ unsigned short Xs[208 * MP];   // 56,576 B
    __shared__ int lastFlag;
    __shared__ float redf[128];
    const int swz = (blockIdx.x & 7) * 190 + (blockIdx.x >> 3);   // bijective
    const int k = swz % K_REL;
    const int bc = swz / K_REL;            // = b*C_CLS + c
    const int c = bc % C_CLS;
    const int b = bc / C_CLS;
    const int kj = (k < c) ? k : k + 1;
    const int tid = threadIdx.x;
    const int lane = tid & 63;
    const int wv = tid >> 6;
    const int l15 = lane & 15;
    const int lq = lane >> 4;

    bf16x8s AF[2][4];
    const unsigned short* ab = Awg + (((size_t)(c * K_REL + k) * 4 + wv) * 8 * 64) * 8;
#pragma unroll
    for (int ut = 0; ut < 2; ut++)
#pragma unroll
        for (int ks = 0; ks < 4; ks++)
            AF[ut][ks] = *(const bf16x8s*)(ab + ((size_t)(ut * 4 + ks) * 64 + lane) * 8);

    const unsigned short* xc = x_objT + ((size_t)(b * C_CLS + c)) * 208 * 64;
    const unsigned short* xk = x_objT + ((size_t)(b * C_CLS + kj)) * 208 * 64;
#pragma unroll
    for (int it = 0; it < 13; it++) {
        int i = tid + it * 256;            // 0..3327
        int hw = i >> 4, ch = i & 15;
        const unsigned short* src = (ch < 8 ? xc : xk) + (size_t)hw * 64 + (ch & 7) * 8;
        *(uint4v*)(&Xs[hw * MP + ch * 8]) = *(const uint4v*)src;
    }
    __syncthreads();

    float csum[2][4];
#pragma unroll
    for (int ut = 0; ut < 2; ut++)
#pragma unroll
        for (int r = 0; r < 4; r++) csum[ut][r] = 0.f;

    for (int t = 0; t < 13; t++) {
        bf16x8s BF[4];
#pragma unroll
        for (int ks = 0; ks < 4; ks++)
            BF[ks] = *(const bf16x8s*)(&Xs[(t * 16 + l15) * MP + ks * 32 + lq * 8]);
        f32x4 acc0 = {0.f, 0.f, 0.f, 0.f}, acc1 = {0.f, 0.f, 0.f, 0.f};
#pragma unroll
        for (int ks = 0; ks < 4; ks++) {
            acc0 = __builtin_amdgcn_mfma_f32_16x16x32_bf16(AF[0][ks], BF[ks], acc0, 0, 0, 0);
            acc1 = __builtin_amdgcn_mfma_f32_16x16x32_bf16(AF[1][ks], BF[ks], acc1, 0, 0, 0);
        }
#pragma unroll
        for (int r = 0; r < 4; r++) {
            csum[0][r] += fmaxf(acc0[r], 0.f);
            csum[1][r] += fmaxf(acc1[r], 0.f);
        }
    }
#pragma unroll
    for (int mask = 1; mask < 16; mask <<= 1) {
#pragma unroll
        for (int ut = 0; ut < 2; ut++)
#pragma unroll
            for (int r = 0; r < 4; r++)
                csum[ut][r] += __shfl_xor(csum[ut][r], mask, 64);
    }
    if (l15 == 0) {
        float* pp = partial + ((size_t)bc * K_REL + k) * U_DIM;
#pragma unroll
        for (int ut = 0; ut < 2; ut++)
#pragma unroll
            for (int r = 0; r < 4; r++)
                pp[wv * 32 + ut * 16 + lq * 4 + r] = csum[ut][r];
    }

    // ---- fused final: last-block-arrival per (b,c) ----
    __threadfence();                       // release our partial writes
    if (tid == 0) {
        int old = atomicAdd(&cnt[bc], 1);  // device-scope
        lastFlag = (old == K_REL - 1);
    }
    __syncthreads();
    if (lastFlag) {
        __threadfence();                   // acquire others' partial writes
        float s = 0.f;
        if (tid < U_DIM) {
            const float* pp = partial + (size_t)bc * K_REL * U_DIM + tid;
            for (int k2 = 0; k2 < K_REL; k2++) s += pp[(size_t)k2 * U_DIM];
            s *= wphi[tid];
        }
        if (tid < 128) redf[tid] = s;
        __syncthreads();
        for (int off = 64; off > 0; off >>= 1) {
            if (tid < off) redf[tid] += redf[tid + off];
            __syncthreads();
        }
        if (tid == 0) out[bc] = redf[0] / (float)NPIX + bphi[0];
    }
}

// ---------------------------------------------------------------------------
extern "C" void kernel_launch(void* const* d_in, const int* in_sizes, int n_in,
                              void* d_out, int out_size, void* d_ws, size_t ws_size,
                              hipStream_t stream) {
    const float* x    = (const float*)d_in[0];
    const float* Wp   = (const float*)d_in[1];
    const float* Wstn = (const float*)d_in[2];
    const float* bstn = (const float*)d_in[3];
    const float* Wg   = (const float*)d_in[4];
    const float* wphi = (const float*)d_in[5];
    const float* bphi = (const float*)d_in[6];
    float* out = (float*)d_out;
    char* wsb = (char*)d_ws;

    unsigned short* xts    = (unsigned short*)(wsb);              //  3,407,872 B
    unsigned short* Awp    = (unsigned short*)(wsb + 3407872);    //  5,242,880 B
    unsigned short* Awg    = (unsigned short*)(wsb + 8650752);    // 12,451,840 B
    unsigned short* x_objT = (unsigned short*)(wsb + 21102592);   //  2,129,920 B
    float* partial         = (float*)(wsb + 23232512);            //    778,240 B
    int* cnt               = (int*)(wsb + 24010752);              //        320 B
    // total 24,011,072 B

    prep_kernel<<<668, 256, 0, stream>>>(x, Wp, Wg, xts, Awp, Awg, cnt);
    gemmphase_kernel<<<80, 512, 0, stream>>>(xts, Awp, Wstn, bstn, x_objT);
    relation_mfma_kernel<<<1520, 256, 0, stream>>>(x_objT, Awg, partial,
                                                   wphi, bphi, cnt, out);
}

// Round 15
// 65.008 us; speedup vs baseline: 2.9941x; 2.9941x over previous
//
#include <hip/hip_runtime.h>

#define FEAT 2048
#define HWD 14
#define NPIX 196          // 14*14
#define C_CLS 20
#define M_DIM 64
#define U_DIM 128
#define B_SZ 4
#define K_REL 19          // C-1
#define NPOOL 49          // 7*7

typedef __attribute__((ext_vector_type(8))) short bf16x8s;
typedef __attribute__((ext_vector_type(8))) unsigned short ushort8v;
typedef __attribute__((ext_vector_type(4))) float f32x4;
typedef __attribute__((ext_vector_type(4))) unsigned int uint4v;

__device__ inline unsigned short f2bf(float f) {
    unsigned u = __builtin_bit_cast(unsigned, f);
    unsigned r = (u + 0x7FFF + ((u >> 16) & 1)) >> 16;   // RNE
    return (unsigned short)r;
}

// ---------------------------------------------------------------------------
// Kernel 1: prep (identical to verified R10 — coalesced in and out).
// ---------------------------------------------------------------------------
__global__ __launch_bounds__(256) void prep_kernel(
        const float* __restrict__ x, const float* __restrict__ Wp,
        const float* __restrict__ Wg,
        unsigned short* __restrict__ xts, unsigned short* __restrict__ Awp,
        unsigned short* __restrict__ Awg) {
    __shared__ unsigned short SM[128 * 136];   // 34,816 B (aliased per branch)
    const int blk = blockIdx.x;
    const int tid = threadIdx.x;
    const int lane = tid & 63, wv = tid >> 6;
    const int l15 = lane & 15, lq = lane >> 4;

    if (blk < 128) {
        unsigned short (*T)[210] = (unsigned short (*)[210])SM;
        const int b = blk >> 5;
        const int s = blk & 31;
        const float* xb = x + ((size_t)b * FEAT + s * 64) * NPIX;
        for (int i = tid; i < 64 * NPIX; i += 256) {
            int kk = i / NPIX, hw = i - kk * NPIX;
            T[kk][hw] = f2bf(xb[(size_t)kk * NPIX + hw]);
        }
        __syncthreads();
        unsigned short* ob = xts + ((size_t)(b * 32 + s)) * 1664 * 8;
        for (int i = tid; i < 1664; i += 256) {
            int ch = i / 208, row = i - ch * 208;
            ushort8v o;
#pragma unroll
            for (int j = 0; j < 8; j++)
                o[j] = (row < NPIX) ? T[ch * 8 + j][row] : (unsigned short)0;
            *(ushort8v*)(ob + (size_t)i * 8) = o;
        }
    } else if (blk < 288) {
        unsigned short (*TP)[264] = (unsigned short (*)[264])SM;
        const int p = blk - 128;
        const int c = p >> 3, kc = p & 7;
        const float* wsrc = Wp + ((size_t)c * M_DIM) * FEAT + kc * 256;
#pragma unroll
        for (int it = 0; it < 16; it++) {
            int i4 = tid + it * 256;           // 0..4095
            int m = i4 >> 6, c4 = i4 & 63;
            float4 v = *(const float4*)(wsrc + (size_t)m * FEAT + c4 * 4);
            TP[m][c4 * 4 + 0] = f2bf(v.x);
            TP[m][c4 * 4 + 1] = f2bf(v.y);
            TP[m][c4 * 4 + 2] = f2bf(v.z);
            TP[m][c4 * 4 + 3] = f2bf(v.w);
        }
        __syncthreads();
#pragma unroll
        for (int fr = 0; fr < 8; fr++) {
            int ss = wv;
            int fi = fr;
            int rt = fi >> 1, f = fi & 1;
            int m = rt * 16 + l15;
            int kl = ss * 64 + f * 32 + lq * 8;
            bf16x8s vfrag = *(const bf16x8s*)(&TP[m][kl]);
            int s = kc * 4 + ss;
            *(bf16x8s*)(Awp + (((size_t)(c * 32 + s) * 8 + fi) * 64 + lane) * 8) = vfrag;
        }
    } else {
        unsigned short (*TG)[136] = (unsigned short (*)[136])SM;
        const int ck = blk - 288;              // 0..379
        const float* gsrc = Wg + (size_t)ck * U_DIM * 128;
#pragma unroll
        for (int it = 0; it < 16; it++) {
            int i4 = tid + it * 256;           // 0..4095
            int u = i4 >> 5, c4 = i4 & 31;
            float4 v = *(const float4*)(gsrc + (size_t)u * 128 + c4 * 4);
            TG[u][c4 * 4 + 0] = f2bf(v.x);
            TG[u][c4 * 4 + 1] = f2bf(v.y);
            TG[u][c4 * 4 + 2] = f2bf(v.z);
            TG[u][c4 * 4 + 3] = f2bf(v.w);
        }
        __syncthreads();
#pragma unroll
        for (int fr = 0; fr < 8; fr++) {
            int fi = fr;
            int ut = fi >> 2, ks = fi & 3;
            int u = wv * 32 + ut * 16 + l15;
            int mm = ks * 32 + lq * 8;
            bf16x8s vfrag = *(const bf16x8s*)(&TG[u][mm]);
            *(bf16x8s*)(Awg + (((size_t)(ck * 4 + wv) * 8 + fi) * 64 + lane) * 8) = vfrag;
        }
    }
}

// ---------------------------------------------------------------------------
// Kernel 2: MERGED gemm + phases. Block=(c,b), 512 thr = 8 waves:
//   kh = wv>>2 (K-half, 16 steps of BK=64), cg = wv&3 (col-tiles {4,3,3,3}).
// K-loop: no LDS, no barriers, direct pre-swizzled global loads, depth-1
// named prefetch. kh0 waves write acc->xs (LDS), barrier, kh1 waves add
// (disjoint addrs, fixed order => determinism). Then pool/theta/sample.
// ---------------------------------------------------------------------------
__global__ __launch_bounds__(512) void gemmphase_kernel(
        const unsigned short* __restrict__ xts,
        const unsigned short* __restrict__ Awp,
        const float* __restrict__ Wstn,
        const float* __restrict__ bstn,
        unsigned short* __restrict__ x_objT) {
    __shared__ __align__(16) char smem[78336];
    float* xs     = (float*)smem;              // [64][209] = 53,504 B
    float* pooled = (float*)(smem + 53504);    // [3136]    = 12,544 B
    float* red    = (float*)(smem + 66048);    // [6][512]  = 12,288 B

    const int c = blockIdx.x, b = blockIdx.y;
    const int tid = threadIdx.x;
    const int lane = tid & 63, wv = tid >> 6;
    const int l15 = lane & 15, lq = lane >> 4;
    const int kh = wv >> 2;                         // K-half
    const int cg = wv & 3;                          // col group
    const int t0 = (cg == 0) ? 0 : (3 * cg + 1);    // {0,4,7,10}
    const int nt = (cg == 0) ? 4 : 3;

    const unsigned short* xsrc = xts + (size_t)b * 32 * 1664 * 8;
    const unsigned short* asrc = Awp + (size_t)c * 256 * 64 * 8;
    const int s0 = kh * 16;

    bf16x8s A0[8], A1[8], B0[8], B1[8];
    auto aload = [&](int s, bf16x8s (&A)[8]) {
#pragma unroll
        for (int fi = 0; fi < 8; fi++)
            A[fi] = *(const bf16x8s*)(asrc + (((size_t)s * 8 + fi) * 64 + lane) * 8);
    };
    auto bload = [&](int s, bf16x8s (&B)[8]) {
#pragma unroll
        for (int q = 0; q < 4; q++) {
            if (q < nt) {
#pragma unroll
                for (int f = 0; f < 2; f++)
                    B[q * 2 + f] = *(const bf16x8s*)(xsrc +
                        ((size_t)s * 1664 + (f * 4 + lq) * 208 + (t0 + q) * 16 + l15) * 8);
            }
        }
    };

    f32x4 acc[4][4];   // [col-tile q][row-frag rt]
#pragma unroll
    for (int q = 0; q < 4; q++)
#pragma unroll
        for (int rt = 0; rt < 4; rt++) acc[q][rt] = (f32x4){0.f, 0.f, 0.f, 0.f};

    auto compute = [&](bf16x8s (&A)[8], bf16x8s (&B)[8]) {
#pragma unroll
        for (int q = 0; q < 4; q++) {
            if (q < nt) {
#pragma unroll
                for (int rt = 0; rt < 4; rt++)
#pragma unroll
                    for (int f = 0; f < 2; f++)
                        acc[q][rt] = __builtin_amdgcn_mfma_f32_16x16x32_bf16(
                            A[rt * 2 + f], B[q * 2 + f], acc[q][rt], 0, 0, 0);
            }
        }
    };

    aload(s0, A0); bload(s0, B0);
#pragma unroll
    for (int sp = 0; sp < 8; sp++) {
        aload(s0 + 2 * sp + 1, A1); bload(s0 + 2 * sp + 1, B1);
        compute(A0, B0);
        if (sp < 7) { aload(s0 + 2 * sp + 2, A0); bload(s0 + 2 * sp + 2, B0); }
        compute(A1, B1);
    }

    // K-half reduce in LDS: kh0 writes, kh1 adds (disjoint per-thread addrs).
    if (kh == 0) {
#pragma unroll
        for (int q = 0; q < 4; q++) {
            if (q < nt) {
                int tt = t0 + q;
#pragma unroll
                for (int rt = 0; rt < 4; rt++)
#pragma unroll
                    for (int r = 0; r < 4; r++)
                        xs[(rt * 16 + lq * 4 + r) * 209 + tt * 16 + l15] = acc[q][rt][r];
            }
        }
    }
    __syncthreads();
    if (kh == 1) {
#pragma unroll
        for (int q = 0; q < 4; q++) {
            if (q < nt) {
                int tt = t0 + q;
#pragma unroll
                for (int rt = 0; rt < 4; rt++)
#pragma unroll
                    for (int r = 0; r < 4; r++)
                        xs[(rt * 16 + lq * 4 + r) * 209 + tt * 16 + l15] += acc[q][rt][r];
            }
        }
    }
    __syncthreads();

    // pool
    for (int i = tid; i < 3136; i += 512) {
        int m = i / NPOOL, p = i - m * NPOOL;
        int ph = p / 7, pw = p - ph * 7;
        const float* bp = &xs[m * 209 + ph * 2 * HWD + pw * 2];
        float v = fmaxf(fmaxf(bp[0], bp[1]), fmaxf(bp[HWD], bp[HWD + 1]));
        pooled[i] = fmaxf(v, 0.f);
    }
    __syncthreads();

    // theta
    float sj[6] = {0, 0, 0, 0, 0, 0};
#pragma unroll
    for (int it = 0; it < 7; it++) {
        int kk = tid + it * 512;
        if (kk < 3136) {
            float f = pooled[kk];
#pragma unroll
            for (int j = 0; j < 6; j++)
                sj[j] += f * Wstn[((size_t)c * 6 + j) * 3136 + kk];
        }
    }
#pragma unroll
    for (int j = 0; j < 6; j++) red[j * 512 + tid] = sj[j];
    __syncthreads();
    for (int off = 256; off > 0; off >>= 1) {
        if (tid < off) {
#pragma unroll
            for (int j = 0; j < 6; j++)
                red[j * 512 + tid] += red[j * 512 + tid + off];
        }
        __syncthreads();
    }
    float th[6];
#pragma unroll
    for (int j = 0; j < 6; j++) th[j] = red[j * 512] + bstn[c * 6 + j];

    // sample -> x_objT[b,c,hw(208),m]; zero-pad rows 196..207
    unsigned short* obase = x_objT + ((size_t)(b * C_CLS + c) * 208) * 64;
    for (int i = tid; i < 12 * 64; i += 512)
        obase[(size_t)(NPIX + i / 64) * 64 + (i & 63)] = 0;

    const int m = tid & 63;
    const int hwg = tid >> 6;                  // 0..7
    unsigned short* ob = obase + m;
    const float* xrow = &xs[m * 209];
    for (int it = 0; it < 25; it++) {
        int hw = hwg + it * 8;
        if (hw >= NPIX) break;                 // wave-uniform
        int h = hw / HWD, w = hw - h * HWD;
        float fx = -1.f + w * (2.f / 13.f);
        float fy = -1.f + h * (2.f / 13.f);
        float gxn = th[0] * fx + th[1] * fy + th[2];
        float gyn = th[3] * fx + th[4] * fy + th[5];
        float gx = (gxn + 1.f) * 0.5f * (HWD - 1);
        float gy = (gyn + 1.f) * 0.5f * (HWD - 1);
        float x0f = floorf(gx), y0f = floorf(gy);
        int x0 = (int)x0f, y0 = (int)y0f;
        int x1 = x0 + 1, y1 = y0 + 1;
        auto gat = [&](int yi, int xi) -> float {
            bool v = (yi >= 0) & (yi < HWD) & (xi >= 0) & (xi < HWD);
            int yc = min(max(yi, 0), HWD - 1);
            int xc = min(max(xi, 0), HWD - 1);
            return v ? xrow[yc * HWD + xc] : 0.f;
        };
        float xw1 = (float)x1 - gx, xw0 = gx - (float)x0;
        float yw1 = (float)y1 - gy, yw0 = gy - (float)y0;
        float val = gat(y0, x0) * xw1 * yw1 + gat(y0, x1) * xw0 * yw1 +
                    gat(y1, x0) * xw1 * yw0 + gat(y1, x1) * xw0 * yw0;
        ob[(size_t)hw * 64] = f2bf(val);
    }
}

// ---------------------------------------------------------------------------
// Kernel 3: relation via MFMA (identical to verified R10).
// ---------------------------------------------------------------------------
#define MP 136
__global__ __launch_bounds__(256) void relation_mfma_kernel(
        const unsigned short* __restrict__ x_objT,
        const unsigned short* __restrict__ Awg,
        float* __restrict__ partial) {
    __shared__ unsigned short Xs[208 * MP];   // 56,576 B
    const int k = blockIdx.x;
    const int c = blockIdx.y;
    const int b = blockIdx.z;
    const int kj = (k < c) ? k : k + 1;
    const int tid = threadIdx.x;
    const int lane = tid & 63;
    const int wv = tid >> 6;
    const int l15 = lane & 15;
    const int lq = lane >> 4;

    bf16x8s AF[2][4];
    const unsigned short* ab = Awg + (((size_t)(c * K_REL + k) * 4 + wv) * 8 * 64) * 8;
#pragma unroll
    for (int ut = 0; ut < 2; ut++)
#pragma unroll
        for (int ks = 0; ks < 4; ks++)
            AF[ut][ks] = *(const bf16x8s*)(ab + ((size_t)(ut * 4 + ks) * 64 + lane) * 8);

    const unsigned short* xc = x_objT + ((size_t)(b * C_CLS + c)) * 208 * 64;
    const unsigned short* xk = x_objT + ((size_t)(b * C_CLS + kj)) * 208 * 64;
#pragma unroll
    for (int it = 0; it < 13; it++) {
        int i = tid + it * 256;            // 0..3327
        int hw = i >> 4, ch = i & 15;
        const unsigned short* src = (ch < 8 ? xc : xk) + (size_t)hw * 64 + (ch & 7) * 8;
        *(uint4v*)(&Xs[hw * MP + ch * 8]) = *(const uint4v*)src;
    }
    __syncthreads();

    float csum[2][4];
#pragma unroll
    for (int ut = 0; ut < 2; ut++)
#pragma unroll
        for (int r = 0; r < 4; r++) csum[ut][r] = 0.f;

    for (int t = 0; t < 13; t++) {
        bf16x8s BF[4];
#pragma unroll
        for (int ks = 0; ks < 4; ks++)
            BF[ks] = *(const bf16x8s*)(&Xs[(t * 16 + l15) * MP + ks * 32 + lq * 8]);
        f32x4 acc0 = {0.f, 0.f, 0.f, 0.f}, acc1 = {0.f, 0.f, 0.f, 0.f};
#pragma unroll
        for (int ks = 0; ks < 4; ks++) {
            acc0 = __builtin_amdgcn_mfma_f32_16x16x32_bf16(AF[0][ks], BF[ks], acc0, 0, 0, 0);
            acc1 = __builtin_amdgcn_mfma_f32_16x16x32_bf16(AF[1][ks], BF[ks], acc1, 0, 0, 0);
        }
#pragma unroll
        for (int r = 0; r < 4; r++) {
            csum[0][r] += fmaxf(acc0[r], 0.f);
            csum[1][r] += fmaxf(acc1[r], 0.f);
        }
    }
#pragma unroll
    for (int mask = 1; mask < 16; mask <<= 1) {
#pragma unroll
        for (int ut = 0; ut < 2; ut++)
#pragma unroll
            for (int r = 0; r < 4; r++)
                csum[ut][r] += __shfl_xor(csum[ut][r], mask, 64);
    }
    if (l15 == 0) {
        float* pp = partial + (((size_t)b * C_CLS + c) * K_REL + k) * U_DIM;
#pragma unroll
        for (int ut = 0; ut < 2; ut++)
#pragma unroll
            for (int r = 0; r < 4; r++)
                pp[wv * 32 + ut * 16 + lq * 4 + r] = csum[ut][r];
    }
}

// ---------------------------------------------------------------------------
// Kernel 4: out[b,c]
// ---------------------------------------------------------------------------
__global__ __launch_bounds__(128) void final_kernel(
        const float* __restrict__ partial, const float* __restrict__ wphi,
        const float* __restrict__ bphi, float* __restrict__ out) {
    int bc = blockIdx.x;
    int u = threadIdx.x;
    float s = 0.f;
    for (int k = 0; k < K_REL; k++)
        s += partial[((size_t)bc * K_REL + k) * U_DIM + u];
    s *= wphi[u];
    __shared__ float red[128];
    red[u] = s;
    __syncthreads();
    for (int off = 64; off > 0; off >>= 1) {
        if (u < off) red[u] += red[u + off];
        __syncthreads();
    }
    if (u == 0) out[bc] = red[0] / (float)NPIX + bphi[0];
}

// ---------------------------------------------------------------------------
extern "C" void kernel_launch(void* const* d_in, const int* in_sizes, int n_in,
                              void* d_out, int out_size, void* d_ws, size_t ws_size,
                              hipStream_t stream) {
    const float* x    = (const float*)d_in[0];
    const float* Wp   = (const float*)d_in[1];
    const float* Wstn = (const float*)d_in[2];
    const float* bstn = (const float*)d_in[3];
    const float* Wg   = (const float*)d_in[4];
    const float* wphi = (const float*)d_in[5];
    const float* bphi = (const float*)d_in[6];
    float* out = (float*)d_out;
    char* wsb = (char*)d_ws;

    unsigned short* xts    = (unsigned short*)(wsb);              //  3,407,872 B
    unsigned short* Awp    = (unsigned short*)(wsb + 3407872);    //  5,242,880 B
    unsigned short* Awg    = (unsigned short*)(wsb + 8650752);    // 12,451,840 B
    unsigned short* x_objT = (unsigned short*)(wsb + 21102592);   //  2,129,920 B
    float* partial         = (float*)(wsb + 23232512);            //    778,240 B
    // total 24,010,752 B

    prep_kernel<<<668, 256, 0, stream>>>(x, Wp, Wg, xts, Awp, Awg);
    gemmphase_kernel<<<dim3(C_CLS, B_SZ), 512, 0, stream>>>(xts, Awp, Wstn, bstn, x_objT);
    relation_mfma_kernel<<<dim3(K_REL, C_CLS, B_SZ), 256, 0, stream>>>(x_objT, Awg, partial);
    final_kernel<<<80, 128, 0, stream>>>(partial, wphi, bphi, out);
}